// Round 11
// baseline (555.770 us; speedup 1.0000x reference)
//
#include <hip/hip_runtime.h>
#include <hip/hip_fp16.h>

// R9: per-XCD replica accumulation with L2-point (non-coherent) f32 atomics,
// fp16-packed coords (8B/atom -> 16MB working set), nontemporal stream loads.
// rep[xcd*N + a0] += v with plain global_atomic_add_f32 (no sc1): atomic at
// the local XCD's TCC only -- safe because each XCD owns its replica, and
// XCC_ID is read from hardware. Kernel-boundary L2 flush makes the reduce
// kernel's cross-XCD reads coherent.

typedef int   vi4 __attribute__((ext_vector_type(4)));
typedef float vf2 __attribute__((ext_vector_type(2)));

struct alignas(8) H4 { __half2 xy; __half2 zw; };

__global__ void pack_xyz_half_kernel(const float* __restrict__ xyz,
                                     H4* __restrict__ xyzh, int n_atoms) {
    int i = blockIdx.x * blockDim.x + threadIdx.x;
    if (i < n_atoms) {
        const float* p = xyz + (size_t)i * 3;
        H4 h;
        h.xy = __floats2half2_rn(p[0], p[1]);
        h.zw = __floats2half2_rn(p[2], 0.0f);
        xyzh[i] = h;
    }
}

__device__ __forceinline__ float3 load_h4(const H4* __restrict__ base, int idx) {
    union { vf2 v; __half2 h[2]; } u;
    u.v = *((const vf2*)base + idx);        // one 8B load
    float2 fxy = __half22float2(u.h[0]);
    float2 fzw = __half22float2(u.h[1]);
    return make_float3(fxy.x, fxy.y, fzw.x);
}

__device__ __forceinline__ void l2_atomic_add(float* p, float v) {
    // No sc0/sc1: performed at the local XCD's L2 (not device-coherent).
    asm volatile("global_atomic_add_f32 %0, %1, off" :: "v"(p), "v"(v) : "memory");
}

// Two bonds per thread, accumulate into this XCD's replica.
__global__ void bond_energy_rep2_kernel(const H4* __restrict__ xyzh,
                                        const vi4* __restrict__ adj2,   // [E/2]
                                        const float* __restrict__ blen,
                                        const float* __restrict__ bpar,
                                        float* __restrict__ rep,
                                        int n_atoms, int n_pairs) {
    int i = blockIdx.x * blockDim.x + threadIdx.x;
    if (i >= n_pairs) return;

    unsigned xcd;
    asm("s_getreg_b32 %0, hwreg(HW_REG_XCC_ID)" : "=s"(xcd));
    float* myrep = rep + (size_t)(xcd & 7) * n_atoms;

    vi4 ab = __builtin_nontemporal_load(adj2 + i);
    vf2 bl = __builtin_nontemporal_load((const vf2*)blen + i);
    vf2 bp = __builtin_nontemporal_load((const vf2*)bpar + i);

    float3 a0 = load_h4(xyzh, ab.x);
    float3 a1 = load_h4(xyzh, ab.y);
    float3 b0 = load_h4(xyzh, ab.z);
    float3 b1 = load_h4(xyzh, ab.w);

    float dx0 = a0.x - a1.x, dy0 = a0.y - a1.y, dz0 = a0.z - a1.z;
    float dx1 = b0.x - b1.x, dy1 = b0.y - b1.y, dz1 = b0.z - b1.z;

    float e0 = sqrtf(dx0 * dx0 + dy0 * dy0 + dz0 * dz0);
    float e1 = sqrtf(dx1 * dx1 + dy1 * dy1 + dz1 * dz1);

    float d0 = e0 - bl.x;
    float d1 = e1 - bl.y;
    float v0 = 0.5f * bp.x * d0 * d0;
    float v1 = 0.5f * bp.y * d1 * d1;

    l2_atomic_add(&myrep[ab.x], v0);
    l2_atomic_add(&myrep[ab.z], v1);
}

__global__ void reduce_rep_kernel(const float* __restrict__ rep,
                                  float* __restrict__ out, int n_atoms) {
    int i = blockIdx.x * blockDim.x + threadIdx.x;
    if (i < n_atoms) {
        float s = 0.0f;
        #pragma unroll
        for (int x = 0; x < 8; ++x) s += rep[(size_t)x * n_atoms + i];
        out[i] = s;
    }
}

// ---- fallbacks (previous verified path) ----

__global__ void pad_xyz_kernel(const float* __restrict__ xyz,
                               float4* __restrict__ xyz4, int n_atoms) {
    int i = blockIdx.x * blockDim.x + threadIdx.x;
    if (i < n_atoms) {
        const float* p = xyz + (size_t)i * 3;
        xyz4[i] = make_float4(p[0], p[1], p[2], 0.0f);
    }
}

__global__ void bond_energy2_kernel(const float4* __restrict__ xyz4,
                                    const int4* __restrict__ adj2,
                                    const float2* __restrict__ blen2,
                                    const float2* __restrict__ bpar2,
                                    float* __restrict__ out,
                                    int n_pairs) {
    int i = blockIdx.x * blockDim.x + threadIdx.x;
    if (i >= n_pairs) return;
    int4   ab = adj2[i];
    float2 bl = blen2[i];
    float2 bp = bpar2[i];
    float4 a0 = xyz4[ab.x];
    float4 a1 = xyz4[ab.y];
    float4 b0 = xyz4[ab.z];
    float4 b1 = xyz4[ab.w];
    float dx0 = a0.x - a1.x, dy0 = a0.y - a1.y, dz0 = a0.z - a1.z;
    float dx1 = b0.x - b1.x, dy1 = b0.y - b1.y, dz1 = b0.z - b1.z;
    float e0 = sqrtf(dx0 * dx0 + dy0 * dy0 + dz0 * dz0);
    float e1 = sqrtf(dx1 * dx1 + dy1 * dy1 + dz1 * dz1);
    float d0 = e0 - bl.x;
    float d1 = e1 - bl.y;
    float v0 = 0.5f * bp.x * d0 * d0;
    float v1 = 0.5f * bp.y * d1 * d1;
    atomicAdd(&out[ab.x], v0);
    atomicAdd(&out[ab.z], v1);
}

__global__ void bond_energy_kernel(const float* __restrict__ xyz,
                                   const int2* __restrict__ adj,
                                   const float* __restrict__ blen,
                                   const float* __restrict__ bpar,
                                   float* __restrict__ out,
                                   int n_bonds) {
    int i = blockIdx.x * blockDim.x + threadIdx.x;
    if (i >= n_bonds) return;
    int2 ab = adj[i];
    const float* p0 = xyz + (size_t)ab.x * 3;
    const float* p1 = xyz + (size_t)ab.y * 3;
    float dx = p0[0] - p1[0];
    float dy = p0[1] - p1[1];
    float dz = p0[2] - p1[2];
    float e = sqrtf(dx * dx + dy * dy + dz * dz);
    float d = e - blen[i];
    float v = 0.5f * bpar[i] * d * d;
    atomicAdd(&out[ab.x], v);
}

extern "C" void kernel_launch(void* const* d_in, const int* in_sizes, int n_in,
                              void* d_out, int out_size, void* d_ws, size_t ws_size,
                              hipStream_t stream) {
    const float* xyz  = (const float*)d_in[0];
    const int*   adj  = (const int*)d_in[1];
    const float* blen = (const float*)d_in[2];
    const float* bpar = (const float*)d_in[3];
    float* out = (float*)d_out;

    const int n_bonds = in_sizes[1] / 2;   // [E,2] flat
    const int n_atoms = in_sizes[0] / 3;   // [N,3] flat

    const int block = 256;
    const size_t packB = (size_t)n_atoms * sizeof(H4);          // 16 MB
    const size_t repB  = (size_t)n_atoms * 8u * sizeof(float);  // 64 MB
    const size_t padB  = (size_t)n_atoms * 4 * sizeof(float);   // 32 MB

    if (ws_size >= packB + repB && (n_bonds & 1) == 0) {
        H4*    xyzh = (H4*)d_ws;
        float* rep  = (float*)((char*)d_ws + packB);
        (void)hipMemsetAsync(rep, 0, repB, stream);
        pack_xyz_half_kernel<<<(n_atoms + block - 1) / block, block, 0, stream>>>(
            xyz, xyzh, n_atoms);
        const int n_pairs = n_bonds / 2;
        bond_energy_rep2_kernel<<<(n_pairs + block - 1) / block, block, 0, stream>>>(
            xyzh, (const vi4*)adj, blen, bpar, rep, n_atoms, n_pairs);
        reduce_rep_kernel<<<(n_atoms + block - 1) / block, block, 0, stream>>>(
            rep, out, n_atoms);
    } else if (ws_size >= padB && (n_bonds & 1) == 0) {
        (void)hipMemsetAsync(d_out, 0, (size_t)out_size * sizeof(float), stream);
        float4* xyz4 = (float4*)d_ws;
        pad_xyz_kernel<<<(n_atoms + block - 1) / block, block, 0, stream>>>(
            xyz, xyz4, n_atoms);
        const int n_pairs = n_bonds / 2;
        bond_energy2_kernel<<<(n_pairs + block - 1) / block, block, 0, stream>>>(
            xyz4, (const int4*)adj, (const float2*)blen, (const float2*)bpar,
            out, n_pairs);
    } else {
        (void)hipMemsetAsync(d_out, 0, (size_t)out_size * sizeof(float), stream);
        bond_energy_kernel<<<(n_bonds + block - 1) / block, block, 0, stream>>>(
            xyz, (const int2*)adj, blen, bpar, out, n_bonds);
    }
}